// Round 1
// baseline (819.572 us; speedup 1.0000x reference)
//
#include <hip/hip_runtime.h>
#include <math.h>

constexpr int BB = 64, NN = 512, DD = 128, UU = 64;
constexpr float KCOUL = 14.399645351950548f;
constexpr float NOISEF = 1e-8f;
#define M_PIF 3.14159265358979323846f

// ---------------- chi MLP: one wave (64 lanes) per row, 4 rows/block ----------
__global__ __launch_bounds__(256) void chi_kernel(
    const float* __restrict__ feats, const float* __restrict__ W1,
    const float* __restrict__ b1, const float* __restrict__ W2,
    const float* __restrict__ b2, const float* __restrict__ W3,
    const float* __restrict__ b3, float* __restrict__ chi)
{
  int wave = threadIdx.x >> 6, lane = threadIdx.x & 63;
  int row = (blockIdx.x << 2) + wave;
  __shared__ float sf[4][DD];
  __shared__ float sh[4][UU];
  const float* f = feats + (size_t)row * DD;
  sf[wave][lane] = f[lane];
  sf[wave][lane + 64] = f[lane + 64];
  __syncthreads();
  float a = b1[lane];
  #pragma unroll 8
  for (int d = 0; d < DD; ++d) a = fmaf(sf[wave][d], W1[d * UU + lane], a);
  float h1 = a - tanhf(a);            // tanhshrink
  sh[wave][lane] = h1;
  __syncthreads();
  float a2 = b2[lane];
  #pragma unroll 8
  for (int i = 0; i < UU; ++i) a2 = fmaf(sh[wave][i], W2[i * UU + lane], a2);
  float h2 = a2 - tanhf(a2);
  float prod = h2 * W3[lane];
  #pragma unroll
  for (int off = 32; off; off >>= 1) prod += __shfl_down(prod, off, 64);
  if (lane == 0) {
    float z = prod + b3[0];
    chi[row] = z - tanhf(z);
  }
}

// ---------------- build A (written straight into d_out's A region) ------------
__global__ __launch_bounds__(256) void build_A_kernel(
    const float* __restrict__ pos, const int* __restrict__ ntype,
    const float* __restrict__ hardness, const float* __restrict__ sigma,
    float* __restrict__ Aout)
{
  int b = blockIdx.y;
  int r0 = blockIdx.x * 16;
  __shared__ float px[NN], py[NN], pz[NN], s2[NN], hd[NN];
  for (int n = threadIdx.x; n < NN; n += 256) {
    const float* p = pos + ((size_t)b * NN + n) * 3;
    px[n] = p[0]; py[n] = p[1]; pz[n] = p[2];
    int ty = ntype[b * NN + n];
    float s = sigma[ty];
    s2[n] = s * s;
    hd[n] = hardness[ty];
  }
  __syncthreads();
  int c0 = (threadIdx.x & 127) << 2;   // 4 consecutive cols per thread
  int rsub = threadIdx.x >> 7;         // 2 rows in flight
  float* outB = Aout + (size_t)b * NN * NN;
  for (int k = 0; k < 8; ++k) {
    int i = r0 + (k << 1) + rsub;
    float pxi = px[i], pyi = py[i], pzi = pz[i], s2i = s2[i];
    float4 v;
    float* vp = &v.x;
    #pragma unroll
    for (int c = 0; c < 4; ++c) {
      int j = c0 + c;
      float dx = pxi - px[j], dy = pyi - py[j], dz = pzi - pz[j];
      float d = sqrtf(fmaf(dx, dx, fmaf(dy, dy, dz * dz))) + NOISEF;
      // arg = d / (sqrt(2)*gamma_ij),  gamma_ij = sqrt(s2i+s2j)
      float arg = d * rsqrtf(2.0f * (s2i + s2[j]));
      float val = KCOUL * erff(arg) / d;
      if (j == i) val += hd[i] + KCOUL * rsqrtf(2.0f * M_PIF * s2i); // + k/(sqrt(pi)*sqrt(2)*sig)
      vp[c] = val;
    }
    *reinterpret_cast<float4*>(outB + (size_t)i * NN + c0) = v;
  }
}

// ---------------- batched 2-RHS CG on the bordered system ---------------------
__device__ __forceinline__ float2 blockReduce2(float2 v, float2* wred, int t) {
  #pragma unroll
  for (int off = 32; off; off >>= 1) {
    v.x += __shfl_down(v.x, off, 64);
    v.y += __shfl_down(v.y, off, 64);
  }
  __syncthreads();                       // protects wred reuse
  if ((t & 63) == 0) wred[t >> 6] = v;
  __syncthreads();
  float2 r = wred[0];
  #pragma unroll
  for (int k = 1; k < 16; ++k) { r.x += wred[k].x; r.y += wred[k].y; }
  return r;                              // identical in all threads
}

__global__ __launch_bounds__(1024) void cg_kernel(
    const float* __restrict__ Aall, const float* __restrict__ tq,
    float* qout /* in: chi, out: charges (same region of d_out) */)
{
  int b = blockIdx.x;
  const float* A = Aall + (size_t)b * NN * NN;
  int t = threadIdx.x;
  int i = t & 511;
  int half = t >> 9;
  __shared__ float2 p01[NN], q01[NN], r01[NN], x01[NN];
  __shared__ float2 part[2][NN];
  __shared__ float2 wred[16];

  float2 z2 = make_float2(0.f, 0.f);
  float2 rsq = z2;
  if (half == 0) {
    float b0 = -qout[b * NN + i];        // rhs0 = -chi ; rhs1 = ones
    x01[i] = z2;
    r01[i] = make_float2(b0, 1.0f);
    p01[i] = make_float2(b0, 1.0f);
    rsq = make_float2(b0 * b0, 1.0f);
  }
  float2 rr = blockReduce2(rsq, wred, t);
  float tol0 = fmaxf(1e-10f * rr.x, 1e-10f);  // rel 1e-5 with abs floor
  float tol1 = 1e-10f * rr.y;

  for (int it = 0; it < 120; ++it) {
    bool act0 = rr.x > tol0, act1 = rr.y > tol1;
    if (!act0 && !act1) break;
    // q = A p via symmetry: column scan, lane-coalesced
    float2 acc = z2;
    const float* ap = A + (size_t)(half * 256) * NN + i;
    #pragma unroll 4
    for (int j = half * 256; j < half * 256 + 256; ++j) {
      float a = *ap; ap += NN;
      float2 pj = p01[j];                 // LDS broadcast
      acc.x = fmaf(a, pj.x, acc.x);
      acc.y = fmaf(a, pj.y, acc.y);
    }
    part[half][i] = acc;
    __syncthreads();
    float2 dv = z2;
    if (t < NN) {
      float2 qa = part[0][t], qb = part[1][t];
      qa.x += qb.x; qa.y += qb.y;
      q01[t] = qa;
      float2 pv = p01[t];
      dv.x = qa.x * pv.x;
      dv.y = qa.y * pv.y;
    }
    float2 pq = blockReduce2(dv, wred, t);
    float al0 = act0 ? rr.x / pq.x : 0.f;
    float al1 = act1 ? rr.y / pq.y : 0.f;
    float2 rn = z2;
    if (t < NN) {
      float2 xv = x01[t], rv = r01[t], pv = p01[t], qv = q01[t];
      xv.x = fmaf(al0, pv.x, xv.x);  xv.y = fmaf(al1, pv.y, xv.y);
      rv.x = fmaf(-al0, qv.x, rv.x); rv.y = fmaf(-al1, qv.y, rv.y);
      x01[t] = xv; r01[t] = rv;
      rn.x = rv.x * rv.x; rn.y = rv.y * rv.y;
    }
    float2 rrn = blockReduce2(rn, wred, t);
    float be0 = act0 ? rrn.x / rr.x : 0.f;
    float be1 = act1 ? rrn.y / rr.y : 0.f;
    if (t < NN) {
      float2 rv = r01[t], pv = p01[t];
      pv.x = fmaf(be0, pv.x, rv.x);
      pv.y = fmaf(be1, pv.y, rv.y);
      p01[t] = pv;
    }
    rr = rrn;
    __syncthreads();                      // p01 ready for next matvec
  }
  // epilogue: lambda = (1'y - Q)/(1'z);  charges = y - lambda*z
  float2 sv = z2;
  if (t < NN) sv = x01[t];
  float2 s = blockReduce2(sv, wred, t);
  float lam = (s.x - tq[b]) / s.y;
  if (t < NN) qout[b * NN + t] = x01[t].x - lam * x01[t].y;
}

extern "C" void kernel_launch(void* const* d_in, const int* in_sizes, int n_in,
                              void* d_out, int out_size, void* d_ws, size_t ws_size,
                              hipStream_t stream) {
  const float* pos      = (const float*)d_in[0];
  const float* feats    = (const float*)d_in[1];
  const int*   ntype    = (const int*)  d_in[2];
  const float* tq       = (const float*)d_in[3];
  const float* hardness = (const float*)d_in[4];
  const float* sigma    = (const float*)d_in[5];
  const float* W1 = (const float*)d_in[6];
  const float* b1 = (const float*)d_in[7];
  const float* W2 = (const float*)d_in[8];
  const float* b2 = (const float*)d_in[9];
  const float* W3 = (const float*)d_in[10];
  const float* b3 = (const float*)d_in[11];

  float* out  = (float*)d_out;
  float* chi  = out;             // charges region doubles as chi scratch
  float* Aout = out + BB * NN;   // output 1: A, batch-major

  chi_kernel<<<dim3(BB * NN / 4), dim3(256), 0, stream>>>(feats, W1, b1, W2, b2, W3, b3, chi);
  build_A_kernel<<<dim3(NN / 16, BB), dim3(256), 0, stream>>>(pos, ntype, hardness, sigma, Aout);
  cg_kernel<<<dim3(BB), dim3(1024), 0, stream>>>(Aout, tq, chi);
}